// Round 1
// baseline (84.989 us; speedup 1.0000x reference)
//
#include <hip/hip_runtime.h>

#define B_ 4
#define L_ 512
#define D_ 100

__device__ __forceinline__ float fexp2(float x) { return __builtin_amdgcn_exp2f(x); }
__device__ __forceinline__ float frcp(float x)  { return __builtin_amdgcn_rcpf(x); }

// ---------------------------------------------------------------------------
// K1: S[b,q,k] = dot(x_q, x_k) ; T[b,q,k] = sum_d tanh(x_q[d] + x_k[d])
// Both symmetric in (q,k): only kt>=qt blocks work, mirror-write the rest.
// Inputs staged into LDS pre-scaled by C=2*log2(e) so tanh arg needs only an
// add before v_exp; dot is corrected by 1/C^2 at the end.
// tanh(x) = 1 - 2*rcp(1+exp2(C*x));  sum_d tanh = D - 2*sum_d rcp(...)
// ---------------------------------------------------------------------------
__global__ __launch_bounds__(256) void k_scores(const float* __restrict__ x,
                                                float* __restrict__ S,
                                                float* __restrict__ T) {
  const int kt = blockIdx.x, qt = blockIdx.y, b = blockIdx.z;
  if (kt < qt) return;  // symmetric: skip lower-triangle tiles
  __shared__ float XQ[32 * 101];  // stride 101 (odd) -> conflict-free b32 reads
  __shared__ float XK[32 * 101];
  const float C = 2.8853900817779268f;                 // 2*log2(e)
  const float INVC2 = 1.0f / (2.8853900817779268f * 2.8853900817779268f);
  const float* xb = x + (size_t)b * L_ * D_;
  const int tid = threadIdx.x;
  for (int i = tid; i < 32 * D_; i += 256) {
    int r = i / D_, c = i - r * D_;
    XQ[r * 101 + c] = xb[(qt * 32 + r) * D_ + c] * C;
    XK[r * 101 + c] = xb[(kt * 32 + r) * D_ + c] * C;
  }
  __syncthreads();
  const int tx = tid & 15, ty = tid >> 4;
  float s00 = 0, s01 = 0, s10 = 0, s11 = 0;
  float r00 = 0, r01 = 0, r10 = 0, r11 = 0;
  const float* qp0 = &XQ[ty * 101];
  const float* qp1 = &XQ[(ty + 16) * 101];
  const float* kp0 = &XK[tx * 101];
  const float* kp1 = &XK[(tx + 16) * 101];
#pragma unroll 4
  for (int d = 0; d < D_; ++d) {
    float a0 = qp0[d], a1 = qp1[d], b0 = kp0[d], b1 = kp1[d];
    s00 += a0 * b0; s01 += a0 * b1; s10 += a1 * b0; s11 += a1 * b1;
    r00 += frcp(1.0f + fexp2(a0 + b0));
    r01 += frcp(1.0f + fexp2(a0 + b1));
    r10 += frcp(1.0f + fexp2(a1 + b0));
    r11 += frcp(1.0f + fexp2(a1 + b1));
  }
  s00 *= INVC2; s01 *= INVC2; s10 *= INVC2; s11 *= INVC2;
  float t00 = (float)D_ - 2.0f * r00;
  float t01 = (float)D_ - 2.0f * r01;
  float t10 = (float)D_ - 2.0f * r10;
  float t11 = (float)D_ - 2.0f * r11;
  const int q0 = qt * 32 + ty, q1 = q0 + 16;
  const int k0 = kt * 32 + tx, k1 = k0 + 16;
  float* Sb = S + (size_t)b * L_ * L_;
  float* Tb = T + (size_t)b * L_ * L_;
  Sb[q0 * L_ + k0] = s00; Sb[q0 * L_ + k1] = s01;
  Sb[q1 * L_ + k0] = s10; Sb[q1 * L_ + k1] = s11;
  Tb[q0 * L_ + k0] = t00; Tb[q0 * L_ + k1] = t01;
  Tb[q1 * L_ + k0] = t10; Tb[q1 * L_ + k1] = t11;
  if (kt != qt) {  // mirror
    Sb[k0 * L_ + q0] = s00; Sb[k1 * L_ + q0] = s01;
    Sb[k0 * L_ + q1] = s10; Sb[k1 * L_ + q1] = s11;
    Tb[k0 * L_ + q0] = t00; Tb[k1 * L_ + q0] = t01;
    Tb[k0 * L_ + q1] = t10; Tb[k1 * L_ + q1] = t11;
  }
}

// ---------------------------------------------------------------------------
// K2: per (b,q) row: P = w0*softmax(S) + w1*softmax(T) + w2*softmax(S/10),
// written in place over S. w = att_w / sum(att_w). max(S/10) == max(S)/10.
// Also zero-inits the pooled buffer (block (0,0)) for K4's atomicMax.
// ---------------------------------------------------------------------------
__global__ __launch_bounds__(256) void k_softmax(float* __restrict__ S,
                                                 const float* __restrict__ T,
                                                 const float* __restrict__ attw,
                                                 float* __restrict__ pooled) {
  const int q = blockIdx.x, b = blockIdx.y;
  const int tid = threadIdx.x;
  if (q == 0 && b == 0 && tid < B_ * 30) pooled[tid] = 0.0f;
  const float L2E = 1.4426950408889634f;
  size_t row = ((size_t)b * L_ + q) * (size_t)L_;
  float s0 = S[row + tid], s1 = S[row + tid + 256];
  float t0 = T[row + tid], t1 = T[row + tid + 256];
  float ms = fmaxf(s0, s1), mt = fmaxf(t0, t1);
#pragma unroll
  for (int o = 32; o > 0; o >>= 1) {
    ms = fmaxf(ms, __shfl_xor(ms, o));
    mt = fmaxf(mt, __shfl_xor(mt, o));
  }
  __shared__ float red[4][3];
  const int wid = tid >> 6, lane = tid & 63;
  if (lane == 0) { red[wid][0] = ms; red[wid][1] = mt; }
  __syncthreads();
  ms = fmaxf(fmaxf(red[0][0], red[1][0]), fmaxf(red[2][0], red[3][0]));
  mt = fmaxf(fmaxf(red[0][1], red[1][1]), fmaxf(red[2][1], red[3][1]));
  float e10 = fexp2((s0 - ms) * L2E),        e11 = fexp2((s1 - ms) * L2E);
  float e20 = fexp2((t0 - mt) * L2E),        e21 = fexp2((t1 - mt) * L2E);
  float e30 = fexp2((s0 - ms) * (0.1f*L2E)), e31 = fexp2((s1 - ms) * (0.1f*L2E));
  float z1 = e10 + e11, z2 = e20 + e21, z3 = e30 + e31;
#pragma unroll
  for (int o = 32; o > 0; o >>= 1) {
    z1 += __shfl_xor(z1, o);
    z2 += __shfl_xor(z2, o);
    z3 += __shfl_xor(z3, o);
  }
  __syncthreads();  // everyone done reading red before rewrite
  if (lane == 0) { red[wid][0] = z1; red[wid][1] = z2; red[wid][2] = z3; }
  __syncthreads();
  z1 = red[0][0] + red[1][0] + red[2][0] + red[3][0];
  z2 = red[0][1] + red[1][1] + red[2][1] + red[3][1];
  z3 = red[0][2] + red[1][2] + red[2][2] + red[3][2];
  float w0 = attw[0], w1 = attw[1], w2 = attw[2];
  float winv = frcp(w0 + w1 + w2);
  float c1 = w0 * winv * frcp(z1);
  float c2 = w1 * winv * frcp(z2);
  float c3 = w2 * winv * frcp(z3);
  S[row + tid]       = c1 * e10 + c2 * e20 + c3 * e30;
  S[row + tid + 256] = c1 * e11 + c2 * e21 + c3 * e31;
}

// ---------------------------------------------------------------------------
// K3: X2[b,q,d] = src[b,q,d] + sum_k P[b,q,k] * src[b,k,d]
// Block = (b, group of 8 q rows); each 128-thread half owns 4 q rows,
// lane d in [0,100). P rows loaded as float4 (uniform -> L1 broadcast).
// ---------------------------------------------------------------------------
__global__ __launch_bounds__(256) void k_pv(const float* __restrict__ x,
                                            const float* __restrict__ P,
                                            float* __restrict__ X2) {
  const int qg = blockIdx.x, b = blockIdx.y;
  const int tid = threadIdx.x;
  const int d = tid & 127;
  if (d >= D_) return;
  const int q0 = qg * 8 + (tid >> 7) * 4;
  const float* xb = x + (size_t)b * L_ * D_;
  const float* pr = P + ((size_t)b * L_ + q0) * (size_t)L_;
  float a0 = 0, a1 = 0, a2 = 0, a3 = 0;
  for (int k = 0; k < L_; k += 4) {
    float4 p0 = *(const float4*)(pr + k);
    float4 p1 = *(const float4*)(pr + L_ + k);
    float4 p2 = *(const float4*)(pr + 2 * L_ + k);
    float4 p3 = *(const float4*)(pr + 3 * L_ + k);
    float x0 = xb[(k + 0) * D_ + d];
    float x1 = xb[(k + 1) * D_ + d];
    float x2 = xb[(k + 2) * D_ + d];
    float x3 = xb[(k + 3) * D_ + d];
    a0 += p0.x * x0 + p0.y * x1 + p0.z * x2 + p0.w * x3;
    a1 += p1.x * x0 + p1.y * x1 + p1.z * x2 + p1.w * x3;
    a2 += p2.x * x0 + p2.y * x1 + p2.z * x2 + p2.w * x3;
    a3 += p3.x * x0 + p3.y * x1 + p3.z * x2 + p3.w * x3;
  }
  size_t o = (size_t)b * L_ * D_ + (size_t)q0 * D_ + d;
  X2[o]          = xb[(q0 + 0) * D_ + d] + a0;
  X2[o + D_]     = xb[(q0 + 1) * D_ + d] + a1;
  X2[o + 2 * D_] = xb[(q0 + 2) * D_ + d] + a2;
  X2[o + 3 * D_] = xb[(q0 + 3) * D_ + d] + a3;
}

// ---------------------------------------------------------------------------
// K4: conv branches + ReLU + global max-pool (atomicMax into pooled).
// All channels treated as ws=3 with right-aligned zero-padded weights
// (partial-window semantics then match torch padding=(ws-1,ws-1) exactly);
// per-channel valid-t guard t < L+ws-1 excludes positions the reference
// doesn't have. Channel layout: 0-9 ws=1, 10-19 ws=2, 20-29 ws=3.
// ---------------------------------------------------------------------------
__global__ __launch_bounds__(256) void k_conv(const float* __restrict__ X2,
    const float* __restrict__ w1, const float* __restrict__ b1,
    const float* __restrict__ w2, const float* __restrict__ b2,
    const float* __restrict__ w3, const float* __restrict__ b3,
    float* __restrict__ pooled) {
  const int tt = blockIdx.x, cg = blockIdx.y, b = blockIdx.z;
  __shared__ float xs[66 * 101];   // rows t0-2 .. t0+63, stride 101
  __shared__ float wl[8][300];     // 8 channels x (3h x 100d), zero-padded
  const int tid = threadIdx.x;
  const float* xb = X2 + (size_t)b * L_ * D_;
  const int t0 = tt * 64;
  for (int i = tid; i < 66 * D_; i += 256) {
    int r = i / D_, c = i - r * D_;
    int rg = t0 - 2 + r;
    xs[r * 101 + c] = (rg >= 0 && rg < L_) ? xb[rg * D_ + c] : 0.0f;
  }
  for (int i = tid; i < 8 * 300; i += 256) {
    int cl = i / 300, rest = i - cl * 300;
    int h = rest / D_, dd = rest - h * D_;
    int c = cg * 8 + cl;
    float wv = 0.0f;
    if (c < 30) {
      int ws = 1 + c / 10;
      int hh = h - (3 - ws);   // right-align original kernel rows
      if (hh >= 0) {
        if (ws == 1)      wv = w1[c * D_ + dd];
        else if (ws == 2) wv = w2[(c - 10) * 2 * D_ + hh * D_ + dd];
        else              wv = w3[(c - 20) * 3 * D_ + hh * D_ + dd];
      }
    }
    wl[cl][h * D_ + dd] = wv;
  }
  __syncthreads();
  const int tl = tid & 63, g = tid >> 6;
  const int tg = t0 + tl;
  const int cl0 = g, cl1 = g + 4;
  float acc0 = 0, acc1 = 0;
#pragma unroll
  for (int h = 0; h < 3; ++h) {
#pragma unroll 4
    for (int dd = 0; dd < D_; ++dd) {
      float xv = xs[(tl + h) * 101 + dd];
      acc0 += xv * wl[cl0][h * D_ + dd];
      acc1 += xv * wl[cl1][h * D_ + dd];
    }
  }
#pragma unroll
  for (int j = 0; j < 2; ++j) {
    int c = cg * 8 + (j == 0 ? cl0 : cl1);
    float acc = (j == 0) ? acc0 : acc1;
    if (c < 30) {
      int ws = 1 + c / 10;
      float bias = (ws == 1) ? b1[c] : (ws == 2 ? b2[c - 10] : b3[c - 20]);
      float v = (tg < L_ + ws - 1) ? fmaxf(acc + bias, 0.0f) : 0.0f;
#pragma unroll
      for (int o = 32; o > 0; o >>= 1) v = fmaxf(v, __shfl_xor(v, o));
      if (tl == 0)
        atomicMax(reinterpret_cast<int*>(&pooled[b * 30 + c]), __float_as_int(v));
    }
  }
}

// ---------------------------------------------------------------------------
// K5: out[b,j] = pooled[b,:] @ lin_w[:,j] + lin_b[j]
// ---------------------------------------------------------------------------
__global__ void k_linear(const float* __restrict__ pooled,
                         const float* __restrict__ lw,
                         const float* __restrict__ lb,
                         float* __restrict__ out) {
  int i = threadIdx.x;
  if (i >= B_ * 2) return;
  int b = i >> 1, j = i & 1;
  float acc = lb[j];
#pragma unroll
  for (int c = 0; c < 30; ++c) acc += pooled[b * 30 + c] * lw[c * 2 + j];
  out[b * 2 + j] = acc;
}

extern "C" void kernel_launch(void* const* d_in, const int* in_sizes, int n_in,
                              void* d_out, int out_size, void* d_ws, size_t ws_size,
                              hipStream_t stream) {
  const float* src  = (const float*)d_in[0];
  const float* attw = (const float*)d_in[1];
  const float* w1   = (const float*)d_in[2];
  const float* b1   = (const float*)d_in[3];
  const float* w2   = (const float*)d_in[4];
  const float* b2   = (const float*)d_in[5];
  const float* w3   = (const float*)d_in[6];
  const float* b3   = (const float*)d_in[7];
  const float* lw   = (const float*)d_in[8];
  const float* lb   = (const float*)d_in[9];

  // workspace: S (1M f32) | T (1M f32) | X2 (204800 f32) | pooled (120 f32)
  float* S  = (float*)d_ws;
  float* T  = S + (size_t)B_ * L_ * L_;
  float* X2 = T + (size_t)B_ * L_ * L_;
  float* PL = X2 + (size_t)B_ * L_ * D_;
  float* out = (float*)d_out;

  hipLaunchKernelGGL(k_scores,  dim3(16, 16, B_), dim3(256), 0, stream, src, S, T);
  hipLaunchKernelGGL(k_softmax, dim3(L_, B_),     dim3(256), 0, stream, S, T, attw, PL);
  hipLaunchKernelGGL(k_pv,      dim3(L_ / 8, B_), dim3(256), 0, stream, src, S, X2);
  hipLaunchKernelGGL(k_conv,    dim3(9, 4, B_),   dim3(256), 0, stream, X2, w1, b1, w2, b2, w3, b3, PL);
  hipLaunchKernelGGL(k_linear,  dim3(1), dim3(64), 0, stream, PL, lw, lb, out);
}

// Round 2
// 68.082 us; speedup vs baseline: 1.2483x; 1.2483x over previous
//
#include <hip/hip_runtime.h>

#define B_ 4
#define L_ 512
#define D_ 100

__device__ __forceinline__ float fexp2(float x) { return __builtin_amdgcn_exp2f(x); }
__device__ __forceinline__ float frcp(float x)  { return __builtin_amdgcn_rcpf(x); }

// ---------------------------------------------------------------------------
// K1: per 32x32 tile (kt>=qt, symmetric):
//   s = dot(x_q,x_k); t = sum_d tanh(x_q[d]+x_k[d])
//   tanh via exp-product: E[d]=exp2(x[d]*2log2e) precomputed at staging;
//   tanh(u) = 1 - 2*rcp(1+Eq*Ek)  -> 1 trans/element in the d-loop.
//   Then fixed-offset softmax numerators (NO max pass needed):
//     e1 = exp2(s*L2E - 120)   (s <= ~165 -> exp <= 118, no ovf; flushed
//                               terms are >=40 nats below row max (diag))
//     e2 = exp2(t*L2E - 32)    (|t| <= 100 strictly -> exp <= 112.3)
//     e3 = exp2(s*L2E*0.1)     (exp <= ~25)
//   Writes E1/E2/E3 (+mirror) and per-(row,tile) partial sums Zp (no atomics).
// ---------------------------------------------------------------------------
__global__ __launch_bounds__(256) void k_scores(const float* __restrict__ x,
                                                float* __restrict__ E1,
                                                float* __restrict__ E2,
                                                float* __restrict__ E3,
                                                float* __restrict__ Zp) {
  const int kt = blockIdx.x, qt = blockIdx.y, b = blockIdx.z;
  if (kt < qt) return;  // symmetric: skip lower-triangle tiles
  __shared__ float2 XQ[32 * 101];  // (x, exp2(x*C)); stride 101 conflict-free
  __shared__ float2 XK[32 * 101];
  __shared__ float colred[4][16][6];
  const float C = 2.8853900817779268f;  // 2*log2(e)
  const float L2E = 1.4426950408889634f;
  const float* xb = x + (size_t)b * L_ * D_;
  const int tid = threadIdx.x;
  for (int i = tid; i < 32 * D_; i += 256) {
    int r = i / D_, c = i - r * D_;
    float xq = xb[(qt * 32 + r) * D_ + c];
    float xk = xb[(kt * 32 + r) * D_ + c];
    XQ[r * 101 + c] = make_float2(xq, fexp2(xq * C));
    XK[r * 101 + c] = make_float2(xk, fexp2(xk * C));
  }
  __syncthreads();
  const int tx = tid & 15, ty = tid >> 4;
  float s00 = 0, s01 = 0, s10 = 0, s11 = 0;
  float r00 = 0, r01 = 0, r10 = 0, r11 = 0;
  const float2* qp0 = &XQ[ty * 101];
  const float2* qp1 = &XQ[(ty + 16) * 101];
  const float2* kp0 = &XK[tx * 101];
  const float2* kp1 = &XK[(tx + 16) * 101];
#pragma unroll 4
  for (int d = 0; d < D_; ++d) {
    float2 a0 = qp0[d], a1 = qp1[d], b0 = kp0[d], b1 = kp1[d];
    s00 += a0.x * b0.x; s01 += a0.x * b1.x; s10 += a1.x * b0.x; s11 += a1.x * b1.x;
    r00 += frcp(fmaf(a0.y, b0.y, 1.0f));
    r01 += frcp(fmaf(a0.y, b1.y, 1.0f));
    r10 += frcp(fmaf(a1.y, b0.y, 1.0f));
    r11 += frcp(fmaf(a1.y, b1.y, 1.0f));
  }
  float t00 = (float)D_ - 2.0f * r00;
  float t01 = (float)D_ - 2.0f * r01;
  float t10 = (float)D_ - 2.0f * r10;
  float t11 = (float)D_ - 2.0f * r11;
  // softmax numerators with fixed offsets
  float e1_00 = fexp2(fmaf(s00, L2E, -120.0f)), e1_01 = fexp2(fmaf(s01, L2E, -120.0f));
  float e1_10 = fexp2(fmaf(s10, L2E, -120.0f)), e1_11 = fexp2(fmaf(s11, L2E, -120.0f));
  float e2_00 = fexp2(fmaf(t00, L2E, -32.0f)),  e2_01 = fexp2(fmaf(t01, L2E, -32.0f));
  float e2_10 = fexp2(fmaf(t10, L2E, -32.0f)),  e2_11 = fexp2(fmaf(t11, L2E, -32.0f));
  const float L2E10 = 0.14426950408889634f;
  float e3_00 = fexp2(s00 * L2E10), e3_01 = fexp2(s01 * L2E10);
  float e3_10 = fexp2(s10 * L2E10), e3_11 = fexp2(s11 * L2E10);

  const int q0r = qt * 32 + ty, q1r = q0r + 16;
  const int k0 = kt * 32 + tx, k1 = k0 + 16;
  float* E1b = E1 + (size_t)b * L_ * L_;
  float* E2b = E2 + (size_t)b * L_ * L_;
  float* E3b = E3 + (size_t)b * L_ * L_;
  E1b[q0r * L_ + k0] = e1_00; E1b[q0r * L_ + k1] = e1_01;
  E1b[q1r * L_ + k0] = e1_10; E1b[q1r * L_ + k1] = e1_11;
  E2b[q0r * L_ + k0] = e2_00; E2b[q0r * L_ + k1] = e2_01;
  E2b[q1r * L_ + k0] = e2_10; E2b[q1r * L_ + k1] = e2_11;
  E3b[q0r * L_ + k0] = e3_00; E3b[q0r * L_ + k1] = e3_01;
  E3b[q1r * L_ + k0] = e3_10; E3b[q1r * L_ + k1] = e3_11;
  if (kt != qt) {  // mirror (s,t symmetric)
    E1b[k0 * L_ + q0r] = e1_00; E1b[k1 * L_ + q0r] = e1_01;
    E1b[k0 * L_ + q1r] = e1_10; E1b[k1 * L_ + q1r] = e1_11;
    E2b[k0 * L_ + q0r] = e2_00; E2b[k1 * L_ + q0r] = e2_01;
    E2b[k0 * L_ + q1r] = e2_10; E2b[k1 * L_ + q1r] = e2_11;
    E3b[k0 * L_ + q0r] = e3_00; E3b[k1 * L_ + q0r] = e3_01;
    E3b[k0 * L_ + q1r] = e3_10; E3b[k1 * L_ + q1r] = e3_11;
  }

  // ---- row partial sums (over this tile's 32 k's), reduce over tx (wave-local)
  float rs[3][2];
  rs[0][0] = e1_00 + e1_01; rs[0][1] = e1_10 + e1_11;
  rs[1][0] = e2_00 + e2_01; rs[1][1] = e2_10 + e2_11;
  rs[2][0] = e3_00 + e3_01; rs[2][1] = e3_10 + e3_11;
#pragma unroll
  for (int o = 8; o > 0; o >>= 1) {
#pragma unroll
    for (int e = 0; e < 3; ++e) {
      rs[e][0] += __shfl_xor(rs[e][0], o);
      rs[e][1] += __shfl_xor(rs[e][1], o);
    }
  }
  if (tx == 0) {
#pragma unroll
    for (int e = 0; e < 3; ++e) {
      Zp[(((size_t)b * L_ + q0r) * 16 + kt) * 3 + e] = rs[e][0];
      Zp[(((size_t)b * L_ + q1r) * 16 + kt) * 3 + e] = rs[e][1];
    }
  }

  // ---- column partial sums (mirror rows), reduce over ty: in-wave then LDS
  float cs_[3][2];
  cs_[0][0] = e1_00 + e1_10; cs_[0][1] = e1_01 + e1_11;
  cs_[1][0] = e2_00 + e2_10; cs_[1][1] = e2_01 + e2_11;
  cs_[2][0] = e3_00 + e3_10; cs_[2][1] = e3_01 + e3_11;
#pragma unroll
  for (int o = 16; o <= 32; o <<= 1) {  // lane bits 4,5 = ty-in-wave
#pragma unroll
    for (int e = 0; e < 3; ++e) {
      cs_[e][0] += __shfl_xor(cs_[e][0], o);
      cs_[e][1] += __shfl_xor(cs_[e][1], o);
    }
  }
  const int wv = tid >> 6, lane = tid & 63;
  if ((lane >> 4) == 0) {
#pragma unroll
    for (int e = 0; e < 3; ++e) {
      colred[wv][tx][e * 2 + 0] = cs_[e][0];
      colred[wv][tx][e * 2 + 1] = cs_[e][1];
    }
  }
  __syncthreads();
  if (kt != qt && tid < 96) {
    int txx = tid / 6, j = tid - txx * 6;
    float v = colred[0][txx][j] + colred[1][txx][j] + colred[2][txx][j] + colred[3][txx][j];
    int e = j >> 1, half = j & 1;
    int krow = kt * 32 + txx + half * 16;
    Zp[(((size_t)b * L_ + krow) * 16 + qt) * 3 + e] = v;
  }
}

// ---------------------------------------------------------------------------
// K2: fused softmax-normalize + PV partial. Grid (qg=64, ks=4, b).
// Per block: 8 q-rows, 128-k slice. Forms P chunk in LDS from E1..3 and
// per-row coefficients c_i = w_i/sum(w) * rcp(Z_i) (Z from Zp partials),
// then Xp[ks] += P @ x over the k slice. 1024 blocks -> 4 waves/SIMD.
// Also zero-inits pooled for K3's atomicMax (stream-ordered before K3).
// ---------------------------------------------------------------------------
__global__ __launch_bounds__(256) void k_pv(const float* __restrict__ x,
    const float* __restrict__ E1, const float* __restrict__ E2,
    const float* __restrict__ E3, const float* __restrict__ Zp,
    const float* __restrict__ attw,
    float* __restrict__ Xp, float* __restrict__ pooled) {
  const int qg = blockIdx.x, ks = blockIdx.y, b = blockIdx.z;
  const int tid = threadIdx.x;
  if (qg == 0 && ks == 0 && b == 0 && tid < B_ * 30) pooled[tid] = 0.0f;
  __shared__ float cs[8][3];
  __shared__ float P[8][128];
  const int q0 = qg * 8;
  if (tid < 24) {
    int row = tid / 3, j = tid - row * 3;
    const float* zp = Zp + (((size_t)b * L_ + q0 + row) * 16) * 3 + j;
    float z = 0.0f;
#pragma unroll
    for (int t = 0; t < 16; ++t) z += zp[t * 3];
    float winv = frcp(attw[0] + attw[1] + attw[2]);
    cs[row][j] = attw[j] * winv * frcp(z);
  }
  __syncthreads();
  for (int idx = tid; idx < 8 * 128; idx += 256) {
    int row = idx >> 7, kk = idx & 127;
    size_t o = ((size_t)b * L_ + q0 + row) * (size_t)L_ + ks * 128 + kk;
    P[row][kk] = cs[row][0] * E1[o] + cs[row][1] * E2[o] + cs[row][2] * E3[o];
  }
  __syncthreads();
  const int d = tid & 127, qh = tid >> 7;
  if (d >= D_) return;
  const float* xb = x + (size_t)b * L_ * D_ + (size_t)(ks * 128) * D_;
  const int r0 = qh * 4;
  float a0 = 0, a1 = 0, a2 = 0, a3 = 0;
  for (int kk = 0; kk < 128; kk += 4) {
    float4 p0 = *(const float4*)&P[r0 + 0][kk];
    float4 p1 = *(const float4*)&P[r0 + 1][kk];
    float4 p2 = *(const float4*)&P[r0 + 2][kk];
    float4 p3 = *(const float4*)&P[r0 + 3][kk];
    float x0 = xb[(kk + 0) * D_ + d];
    float x1 = xb[(kk + 1) * D_ + d];
    float x2 = xb[(kk + 2) * D_ + d];
    float x3 = xb[(kk + 3) * D_ + d];
    a0 += p0.x * x0 + p0.y * x1 + p0.z * x2 + p0.w * x3;
    a1 += p1.x * x0 + p1.y * x1 + p1.z * x2 + p1.w * x3;
    a2 += p2.x * x0 + p2.y * x1 + p2.z * x2 + p2.w * x3;
    a3 += p3.x * x0 + p3.y * x1 + p3.z * x2 + p3.w * x3;
  }
  size_t o = (((size_t)ks * B_ + b) * L_ + q0 + r0) * D_ + d;
  Xp[o]          = a0;
  Xp[o + D_]     = a1;
  Xp[o + 2 * D_] = a2;
  Xp[o + 3 * D_] = a3;
}

// ---------------------------------------------------------------------------
// K3: conv branches + ReLU + global max-pool (atomicMax into pooled).
// Staging composes x2 = src + sum of the 4 PV k-split partials (deterministic,
// no atomics). Channels right-aligned zero-padded to ws=3 as before.
// ---------------------------------------------------------------------------
__global__ __launch_bounds__(256) void k_conv(const float* __restrict__ src,
    const float* __restrict__ Xp,
    const float* __restrict__ w1, const float* __restrict__ b1,
    const float* __restrict__ w2, const float* __restrict__ b2,
    const float* __restrict__ w3, const float* __restrict__ b3,
    float* __restrict__ pooled) {
  const int tt = blockIdx.x, cg = blockIdx.y, b = blockIdx.z;
  __shared__ float xs[66 * 101];
  __shared__ float wl[8][300];
  const int tid = threadIdx.x;
  const float* xb  = src + (size_t)b * L_ * D_;
  const float* pp0 = Xp + ((size_t)(0 * B_ + b) * L_) * D_;
  const float* pp1 = Xp + ((size_t)(1 * B_ + b) * L_) * D_;
  const float* pp2 = Xp + ((size_t)(2 * B_ + b) * L_) * D_;
  const float* pp3 = Xp + ((size_t)(3 * B_ + b) * L_) * D_;
  const int t0 = tt * 64;
  for (int i = tid; i < 66 * D_; i += 256) {
    int r = i / D_, c = i - r * D_;
    int rg = t0 - 2 + r;
    float v = 0.0f;
    if (rg >= 0 && rg < L_) {
      size_t o = (size_t)rg * D_ + c;
      v = xb[o] + pp0[o] + pp1[o] + pp2[o] + pp3[o];
    }
    xs[r * 101 + c] = v;
  }
  for (int i = tid; i < 8 * 300; i += 256) {
    int cl = i / 300, rest = i - cl * 300;
    int h = rest / D_, dd = rest - h * D_;
    int c = cg * 8 + cl;
    float wv = 0.0f;
    if (c < 30) {
      int ws = 1 + c / 10;
      int hh = h - (3 - ws);
      if (hh >= 0) {
        if (ws == 1)      wv = w1[c * D_ + dd];
        else if (ws == 2) wv = w2[(c - 10) * 2 * D_ + hh * D_ + dd];
        else              wv = w3[(c - 20) * 3 * D_ + hh * D_ + dd];
      }
    }
    wl[cl][h * D_ + dd] = wv;
  }
  __syncthreads();
  const int tl = tid & 63, g = tid >> 6;
  const int tg = t0 + tl;
  const int cl0 = g, cl1 = g + 4;
  float acc0 = 0, acc1 = 0;
#pragma unroll
  for (int h = 0; h < 3; ++h) {
#pragma unroll 4
    for (int dd = 0; dd < D_; ++dd) {
      float xv = xs[(tl + h) * 101 + dd];
      acc0 += xv * wl[cl0][h * D_ + dd];
      acc1 += xv * wl[cl1][h * D_ + dd];
    }
  }
#pragma unroll
  for (int j = 0; j < 2; ++j) {
    int c = cg * 8 + (j == 0 ? cl0 : cl1);
    float acc = (j == 0) ? acc0 : acc1;
    if (c < 30) {
      int ws = 1 + c / 10;
      float bias = (ws == 1) ? b1[c] : (ws == 2 ? b2[c - 10] : b3[c - 20]);
      float v = (tg < L_ + ws - 1) ? fmaxf(acc + bias, 0.0f) : 0.0f;
#pragma unroll
      for (int o = 32; o > 0; o >>= 1) v = fmaxf(v, __shfl_xor(v, o));
      if (tl == 0)
        atomicMax(reinterpret_cast<int*>(&pooled[b * 30 + c]), __float_as_int(v));
    }
  }
}

// ---------------------------------------------------------------------------
// K4: out[b,j] = pooled[b,:] @ lin_w[:,j] + lin_b[j]
// ---------------------------------------------------------------------------
__global__ void k_linear(const float* __restrict__ pooled,
                         const float* __restrict__ lw,
                         const float* __restrict__ lb,
                         float* __restrict__ out) {
  int i = threadIdx.x;
  if (i >= B_ * 2) return;
  int b = i >> 1, j = i & 1;
  float acc = lb[j];
#pragma unroll
  for (int c = 0; c < 30; ++c) acc += pooled[b * 30 + c] * lw[c * 2 + j];
  out[b * 2 + j] = acc;
}

extern "C" void kernel_launch(void* const* d_in, const int* in_sizes, int n_in,
                              void* d_out, int out_size, void* d_ws, size_t ws_size,
                              hipStream_t stream) {
  const float* src  = (const float*)d_in[0];
  const float* attw = (const float*)d_in[1];
  const float* w1   = (const float*)d_in[2];
  const float* b1   = (const float*)d_in[3];
  const float* w2   = (const float*)d_in[4];
  const float* b2   = (const float*)d_in[5];
  const float* w3   = (const float*)d_in[6];
  const float* b3   = (const float*)d_in[7];
  const float* lw   = (const float*)d_in[8];
  const float* lb   = (const float*)d_in[9];

  // ws: E1|E2|E3 (1M f32 each) | Zp (98304) | Xp (819200) | pooled (120)
  float* E1 = (float*)d_ws;
  float* E2 = E1 + (size_t)B_ * L_ * L_;
  float* E3 = E2 + (size_t)B_ * L_ * L_;
  float* Zp = E3 + (size_t)B_ * L_ * L_;
  float* Xp = Zp + (size_t)B_ * L_ * 16 * 3;
  float* PL = Xp + (size_t)4 * B_ * L_ * D_;
  float* out = (float*)d_out;

  hipLaunchKernelGGL(k_scores, dim3(16, 16, B_), dim3(256), 0, stream, src, E1, E2, E3, Zp);
  hipLaunchKernelGGL(k_pv,     dim3(64, 4, B_),  dim3(256), 0, stream, src, E1, E2, E3, Zp, attw, Xp, PL);
  hipLaunchKernelGGL(k_conv,   dim3(9, 4, B_),   dim3(256), 0, stream, src, Xp, w1, b1, w2, b2, w3, b3, PL);
  hipLaunchKernelGGL(k_linear, dim3(1), dim3(64), 0, stream, PL, lw, lb, out);
}

// Round 3
// 58.794 us; speedup vs baseline: 1.4455x; 1.1580x over previous
//
#include <hip/hip_runtime.h>

#define B_ 4
#define L_ 512
#define D_ 100

__device__ __forceinline__ float fexp2(float x) { return __builtin_amdgcn_exp2f(x); }
__device__ __forceinline__ float frcp(float x)  { return __builtin_amdgcn_rcpf(x); }

// ---------------------------------------------------------------------------
// K1: linear-triangle 32x32 tiles (136 per batch), tile (qt,kt) with kt>=qt.
//   s = dot(x_q,x_k); t = sum_d tanh(x_q[d]+x_k[d]) via exp-product:
//   E[d]=exp2(x[d]*2log2e) staged; tanh(u)=1-2*rcp(1+Eq*Ek) -> 1 trans/elem.
//   Fixed-offset softmax numerators (no max pass; see round-2 bounds):
//     e1=exp2(s*L2E-120), e2=exp2(t*L2E-32), e3=exp2(s*L2E/10)
//   LDS: float2 stride 102 -> 16B-aligned float4 reads, 2 d per instr.
//   Mirror writes staged through LDS transpose (reuse XK) -> coalesced.
//   Zp row partials direct; col partials (mirror rows) via shuffles+colred.
//   Block (0,0) also zero-inits pooled + arrival counter for K3.
// ---------------------------------------------------------------------------
__global__ __launch_bounds__(256) void k_scores(const float* __restrict__ x,
                                                float* __restrict__ E1,
                                                float* __restrict__ E2,
                                                float* __restrict__ E3,
                                                float* __restrict__ Zp,
                                                int* __restrict__ counter,
                                                float* __restrict__ pooled) {
  const int b = blockIdx.y;
  const int tid = threadIdx.x;
  if (blockIdx.x == 0 && b == 0) {
    if (tid < B_ * 30) pooled[tid] = 0.0f;
    if (tid == 128) *counter = 0;
  }
  int qt = 0, rem = blockIdx.x;
  while (rem >= 16 - qt) { rem -= (16 - qt); ++qt; }
  const int kt = qt + rem;

  __shared__ float2 XQ[32 * 102];  // (x, exp2(x*C)); even stride -> b128-aligned
  __shared__ float2 XK[32 * 102];
  __shared__ float colred[4][16][6];
  const float C = 2.8853900817779268f;  // 2*log2(e)
  const float L2E = 1.4426950408889634f;
  const float* xb = x + (size_t)b * L_ * D_;
  for (int i = tid; i < 32 * D_; i += 256) {
    int r = i / D_, c = i - r * D_;
    float xq = xb[(qt * 32 + r) * D_ + c];
    float xk = xb[(kt * 32 + r) * D_ + c];
    XQ[r * 102 + c] = make_float2(xq, fexp2(xq * C));
    XK[r * 102 + c] = make_float2(xk, fexp2(xk * C));
  }
  __syncthreads();
  const int tx = tid & 15, ty = tid >> 4;
  float s00 = 0, s01 = 0, s10 = 0, s11 = 0;
  float r00 = 0, r01 = 0, r10 = 0, r11 = 0;
  const float2* qp0 = &XQ[ty * 102];
  const float2* qp1 = &XQ[(ty + 16) * 102];
  const float2* kp0 = &XK[tx * 102];
  const float2* kp1 = &XK[(tx + 16) * 102];
#pragma unroll 2
  for (int d = 0; d < D_; d += 2) {  // 2 d per iter via float4 (b128) reads
    float4 A0 = *(const float4*)&qp0[d];
    float4 A1 = *(const float4*)&qp1[d];
    float4 B0 = *(const float4*)&kp0[d];
    float4 B1 = *(const float4*)&kp1[d];
    s00 += A0.x * B0.x + A0.z * B0.z;
    s01 += A0.x * B1.x + A0.z * B1.z;
    s10 += A1.x * B0.x + A1.z * B0.z;
    s11 += A1.x * B1.x + A1.z * B1.z;
    r00 += frcp(fmaf(A0.y, B0.y, 1.0f)) + frcp(fmaf(A0.w, B0.w, 1.0f));
    r01 += frcp(fmaf(A0.y, B1.y, 1.0f)) + frcp(fmaf(A0.w, B1.w, 1.0f));
    r10 += frcp(fmaf(A1.y, B0.y, 1.0f)) + frcp(fmaf(A1.w, B0.w, 1.0f));
    r11 += frcp(fmaf(A1.y, B1.y, 1.0f)) + frcp(fmaf(A1.w, B1.w, 1.0f));
  }
  float t00 = (float)D_ - 2.0f * r00;
  float t01 = (float)D_ - 2.0f * r01;
  float t10 = (float)D_ - 2.0f * r10;
  float t11 = (float)D_ - 2.0f * r11;
  float e1_00 = fexp2(fmaf(s00, L2E, -120.0f)), e1_01 = fexp2(fmaf(s01, L2E, -120.0f));
  float e1_10 = fexp2(fmaf(s10, L2E, -120.0f)), e1_11 = fexp2(fmaf(s11, L2E, -120.0f));
  float e2_00 = fexp2(fmaf(t00, L2E, -32.0f)),  e2_01 = fexp2(fmaf(t01, L2E, -32.0f));
  float e2_10 = fexp2(fmaf(t10, L2E, -32.0f)),  e2_11 = fexp2(fmaf(t11, L2E, -32.0f));
  const float L2E10 = 0.14426950408889634f;
  float e3_00 = fexp2(s00 * L2E10), e3_01 = fexp2(s01 * L2E10);
  float e3_10 = fexp2(s10 * L2E10), e3_11 = fexp2(s11 * L2E10);

  const int q0r = qt * 32 + ty, q1r = q0r + 16;
  const int k0 = kt * 32 + tx, k1 = k0 + 16;
  float* E1b = E1 + (size_t)b * L_ * L_;
  float* E2b = E2 + (size_t)b * L_ * L_;
  float* E3b = E3 + (size_t)b * L_ * L_;
  E1b[q0r * L_ + k0] = e1_00; E1b[q0r * L_ + k1] = e1_01;
  E1b[q1r * L_ + k0] = e1_10; E1b[q1r * L_ + k1] = e1_11;
  E2b[q0r * L_ + k0] = e2_00; E2b[q0r * L_ + k1] = e2_01;
  E2b[q1r * L_ + k0] = e2_10; E2b[q1r * L_ + k1] = e2_11;
  E3b[q0r * L_ + k0] = e3_00; E3b[q0r * L_ + k1] = e3_01;
  E3b[q1r * L_ + k0] = e3_10; E3b[q1r * L_ + k1] = e3_11;

  // ---- row partial sums over this tile's 32 k (reduce over tx, wave-local)
  float rs[3][2];
  rs[0][0] = e1_00 + e1_01; rs[0][1] = e1_10 + e1_11;
  rs[1][0] = e2_00 + e2_01; rs[1][1] = e2_10 + e2_11;
  rs[2][0] = e3_00 + e3_01; rs[2][1] = e3_10 + e3_11;
#pragma unroll
  for (int o = 8; o > 0; o >>= 1) {
#pragma unroll
    for (int e = 0; e < 3; ++e) {
      rs[e][0] += __shfl_xor(rs[e][0], o);
      rs[e][1] += __shfl_xor(rs[e][1], o);
    }
  }
  if (tx == 0) {
#pragma unroll
    for (int e = 0; e < 3; ++e) {
      Zp[(((size_t)b * L_ + q0r) * 16 + kt) * 3 + e] = rs[e][0];
      Zp[(((size_t)b * L_ + q1r) * 16 + kt) * 3 + e] = rs[e][1];
    }
  }

  // ---- column partial sums (mirror rows): in-wave shuffles then colred LDS
  float cs_[3][2];
  cs_[0][0] = e1_00 + e1_10; cs_[0][1] = e1_01 + e1_11;
  cs_[1][0] = e2_00 + e2_10; cs_[1][1] = e2_01 + e2_11;
  cs_[2][0] = e3_00 + e3_10; cs_[2][1] = e3_01 + e3_11;
#pragma unroll
  for (int o = 16; o <= 32; o <<= 1) {
#pragma unroll
    for (int e = 0; e < 3; ++e) {
      cs_[e][0] += __shfl_xor(cs_[e][0], o);
      cs_[e][1] += __shfl_xor(cs_[e][1], o);
    }
  }
  const int wv = tid >> 6, lane = tid & 63;
  if ((lane >> 4) == 0) {
#pragma unroll
    for (int e = 0; e < 3; ++e) {
      colred[wv][tx][e * 2 + 0] = cs_[e][0];
      colred[wv][tx][e * 2 + 1] = cs_[e][1];
    }
  }
  __syncthreads();  // colred complete; also: all XK reads done (d-loop past)
  if (kt != qt) {
    if (tid < 96) {
      int txx = tid / 6, j = tid - txx * 6;
      float v = colred[0][txx][j] + colred[1][txx][j] + colred[2][txx][j] + colred[3][txx][j];
      int e = j >> 1, half = j & 1;
      int krow = kt * 32 + txx + half * 16;
      Zp[(((size_t)b * L_ + krow) * 16 + qt) * 3 + e] = v;
    }
    // ---- mirror stores via LDS transpose (coalesced rows), reuse XK space
    float* M = (float*)XK;  // needs 32*33 floats, XK has 6528
    const int mo = ty * 33 + tx;
    // E1
    M[mo] = e1_00; M[mo + 16] = e1_01;
    M[mo + 16 * 33] = e1_10; M[mo + 16 * 33 + 16] = e1_11;
    __syncthreads();
#pragma unroll
    for (int j = 0; j < 4; ++j) {
      int idx = tid + 256 * j, kr = idx >> 5, qc = idx & 31;
      E1b[(kt * 32 + kr) * L_ + qt * 32 + qc] = M[qc * 33 + kr];
    }
    __syncthreads();
    // E2
    M[mo] = e2_00; M[mo + 16] = e2_01;
    M[mo + 16 * 33] = e2_10; M[mo + 16 * 33 + 16] = e2_11;
    __syncthreads();
#pragma unroll
    for (int j = 0; j < 4; ++j) {
      int idx = tid + 256 * j, kr = idx >> 5, qc = idx & 31;
      E2b[(kt * 32 + kr) * L_ + qt * 32 + qc] = M[qc * 33 + kr];
    }
    __syncthreads();
    // E3
    M[mo] = e3_00; M[mo + 16] = e3_01;
    M[mo + 16 * 33] = e3_10; M[mo + 16 * 33 + 16] = e3_11;
    __syncthreads();
#pragma unroll
    for (int j = 0; j < 4; ++j) {
      int idx = tid + 256 * j, kr = idx >> 5, qc = idx & 31;
      E3b[(kt * 32 + kr) * L_ + qt * 32 + qc] = M[qc * 33 + kr];
    }
  }
}

// ---------------------------------------------------------------------------
// K2: fused normalize + PV + residual, full k per block with in-block 4-way
// k-split. Block = 1024 threads (16 waves): thread (qh<2, ks<4, d<128).
// P (8 rows x 512 k) formed once in LDS; partials reduced through the same
// LDS space; writes X2 = src + attn directly (single stream for K3).
// Grid 64 x B = 256 blocks -> 4 waves/SIMD.
// ---------------------------------------------------------------------------
__global__ __launch_bounds__(1024) void k_pv(const float* __restrict__ x,
    const float* __restrict__ E1, const float* __restrict__ E2,
    const float* __restrict__ E3, const float* __restrict__ Zp,
    const float* __restrict__ attw, float* __restrict__ X2) {
  const int qg = blockIdx.x, b = blockIdx.y;
  const int tid = threadIdx.x;
  __shared__ float cs[8][3];
  __shared__ float P[8][512];  // 16 KB; reused as reduction buffer R[4][8][128]
  const int q0 = qg * 8;
  if (tid < 24) {
    int row = tid / 3, j = tid - row * 3;
    const float* zp = Zp + (((size_t)b * L_ + q0 + row) * 16) * 3 + j;
    float z = 0.0f;
#pragma unroll
    for (int t = 0; t < 16; ++t) z += zp[t * 3];
    float winv = frcp(attw[0] + attw[1] + attw[2]);
    cs[row][j] = attw[j] * winv * frcp(z);
  }
  __syncthreads();
  for (int idx = tid; idx < 8 * 512; idx += 1024) {
    int row = idx >> 9, kk = idx & 511;
    size_t o = ((size_t)b * L_ + q0 + row) * (size_t)L_ + kk;
    P[row][kk] = cs[row][0] * E1[o] + cs[row][1] * E2[o] + cs[row][2] * E3[o];
  }
  __syncthreads();
  const int d = tid & 127, ks = (tid >> 7) & 3, qh = tid >> 9;
  const int r0 = qh * 4;
  float a0 = 0, a1 = 0, a2 = 0, a3 = 0;
  if (d < D_) {
    const float* xb = x + (size_t)b * L_ * D_ + (size_t)(ks * 128) * D_;
    const int kb = ks * 128;
    for (int kk = 0; kk < 128; kk += 4) {
      float4 p0 = *(const float4*)&P[r0 + 0][kb + kk];
      float4 p1 = *(const float4*)&P[r0 + 1][kb + kk];
      float4 p2 = *(const float4*)&P[r0 + 2][kb + kk];
      float4 p3 = *(const float4*)&P[r0 + 3][kb + kk];
      float x0 = xb[(kk + 0) * D_ + d];
      float x1 = xb[(kk + 1) * D_ + d];
      float x2 = xb[(kk + 2) * D_ + d];
      float x3 = xb[(kk + 3) * D_ + d];
      a0 += p0.x * x0 + p0.y * x1 + p0.z * x2 + p0.w * x3;
      a1 += p1.x * x0 + p1.y * x1 + p1.z * x2 + p1.w * x3;
      a2 += p2.x * x0 + p2.y * x1 + p2.z * x2 + p2.w * x3;
      a3 += p3.x * x0 + p3.y * x1 + p3.z * x2 + p3.w * x3;
    }
  }
  __syncthreads();  // all P reads done; reuse as R[ks][row][d]
  float* R = &P[0][0];
  R[((ks * 8) + r0 + 0) * 128 + d] = a0;
  R[((ks * 8) + r0 + 1) * 128 + d] = a1;
  R[((ks * 8) + r0 + 2) * 128 + d] = a2;
  R[((ks * 8) + r0 + 3) * 128 + d] = a3;
  __syncthreads();
  if (tid < 8 * D_) {
    int row = tid / D_, dd = tid - row * D_;
    float v = R[(0 * 8 + row) * 128 + dd] + R[(1 * 8 + row) * 128 + dd] +
              R[(2 * 8 + row) * 128 + dd] + R[(3 * 8 + row) * 128 + dd];
    size_t o = ((size_t)b * L_ + q0 + row) * D_ + dd;
    X2[o] = x[o] + v;
  }
}

// ---------------------------------------------------------------------------
// K3: conv branches + ReLU + global max-pool (atomicMax into pooled) + fused
// final linear via arrival counter (last block computes the 8 outputs).
// Single input stream X2. Channels right-aligned zero-padded to ws=3.
// ---------------------------------------------------------------------------
__global__ __launch_bounds__(256) void k_conv(const float* __restrict__ X2,
    const float* __restrict__ w1, const float* __restrict__ b1,
    const float* __restrict__ w2, const float* __restrict__ b2,
    const float* __restrict__ w3, const float* __restrict__ b3,
    const float* __restrict__ lw, const float* __restrict__ lb,
    float* __restrict__ pooled, int* __restrict__ counter,
    float* __restrict__ out) {
  const int tt = blockIdx.x, cg = blockIdx.y, b = blockIdx.z;
  __shared__ float xs[66 * 101];
  __shared__ float wl[8][300];
  __shared__ int lastFlag;
  const int tid = threadIdx.x;
  const float* xb = X2 + (size_t)b * L_ * D_;
  const int t0 = tt * 64;
  for (int i = tid; i < 66 * D_; i += 256) {
    int r = i / D_, c = i - r * D_;
    int rg = t0 - 2 + r;
    xs[r * 101 + c] = (rg >= 0 && rg < L_) ? xb[(size_t)rg * D_ + c] : 0.0f;
  }
  for (int i = tid; i < 8 * 300; i += 256) {
    int cl = i / 300, rest = i - cl * 300;
    int h = rest / D_, dd = rest - h * D_;
    int c = cg * 8 + cl;
    float wv = 0.0f;
    if (c < 30) {
      int ws = 1 + c / 10;
      int hh = h - (3 - ws);
      if (hh >= 0) {
        if (ws == 1)      wv = w1[c * D_ + dd];
        else if (ws == 2) wv = w2[(c - 10) * 2 * D_ + hh * D_ + dd];
        else              wv = w3[(c - 20) * 3 * D_ + hh * D_ + dd];
      }
    }
    wl[cl][h * D_ + dd] = wv;
  }
  __syncthreads();
  const int tl = tid & 63, g = tid >> 6;
  const int tg = t0 + tl;
  const int cl0 = g, cl1 = g + 4;
  float acc0 = 0, acc1 = 0;
#pragma unroll
  for (int h = 0; h < 3; ++h) {
#pragma unroll 4
    for (int dd = 0; dd < D_; ++dd) {
      float xv = xs[(tl + h) * 101 + dd];
      acc0 += xv * wl[cl0][h * D_ + dd];
      acc1 += xv * wl[cl1][h * D_ + dd];
    }
  }
#pragma unroll
  for (int j = 0; j < 2; ++j) {
    int c = cg * 8 + (j == 0 ? cl0 : cl1);
    float acc = (j == 0) ? acc0 : acc1;
    if (c < 30) {
      int ws = 1 + c / 10;
      float bias = (ws == 1) ? b1[c] : (ws == 2 ? b2[c - 10] : b3[c - 20]);
      float v = (tg < L_ + ws - 1) ? fmaxf(acc + bias, 0.0f) : 0.0f;
#pragma unroll
      for (int o = 32; o > 0; o >>= 1) v = fmaxf(v, __shfl_xor(v, o));
      if (tl == 0)
        atomicMax(reinterpret_cast<int*>(&pooled[b * 30 + c]), __float_as_int(v));
    }
  }
  // ---- arrival counter: last block computes the linear head
  __syncthreads();  // all waves' atomics issued & drained before counting
  if (tid == 0) {
    __threadfence();
    int old = atomicAdd(counter, 1);
    lastFlag = (old == 9 * 4 * B_ - 1);
  }
  __syncthreads();
  if (lastFlag && tid < B_ * 2) {
    int bb = tid >> 1, j = tid & 1;
    float acc = lb[j];
    int* pI = reinterpret_cast<int*>(pooled);
#pragma unroll
    for (int c = 0; c < 30; ++c) {
      int pi = atomicMax(&pI[bb * 30 + c], 0);  // coherent read (values >= 0)
      acc = fmaf(__int_as_float(pi), lw[c * 2 + j], acc);
    }
    out[bb * 2 + j] = acc;
  }
}

extern "C" void kernel_launch(void* const* d_in, const int* in_sizes, int n_in,
                              void* d_out, int out_size, void* d_ws, size_t ws_size,
                              hipStream_t stream) {
  const float* src  = (const float*)d_in[0];
  const float* attw = (const float*)d_in[1];
  const float* w1   = (const float*)d_in[2];
  const float* b1   = (const float*)d_in[3];
  const float* w2   = (const float*)d_in[4];
  const float* b2   = (const float*)d_in[5];
  const float* w3   = (const float*)d_in[6];
  const float* b3   = (const float*)d_in[7];
  const float* lw   = (const float*)d_in[8];
  const float* lb   = (const float*)d_in[9];

  // ws: E1|E2|E3 (1,048,576 f32 each) | Zp (98,304) | X2 (204,800) | pooled(128) | counter
  float* E1 = (float*)d_ws;
  float* E2 = E1 + (size_t)B_ * L_ * L_;
  float* E3 = E2 + (size_t)B_ * L_ * L_;
  float* Zp = E3 + (size_t)B_ * L_ * L_;
  float* X2 = Zp + (size_t)B_ * L_ * 16 * 3;
  float* PL = X2 + (size_t)B_ * L_ * D_;
  int* counter = (int*)(PL + 128);
  float* out = (float*)d_out;

  hipLaunchKernelGGL(k_scores, dim3(136, B_), dim3(256), 0, stream,
                     src, E1, E2, E3, Zp, counter, PL);
  hipLaunchKernelGGL(k_pv, dim3(L_ / 8, B_), dim3(1024), 0, stream,
                     src, E1, E2, E3, Zp, attw, X2);
  hipLaunchKernelGGL(k_conv, dim3(9, 4, B_), dim3(256), 0, stream,
                     X2, w1, b1, w2, b2, w3, b3, lw, lb, PL, counter, out);
}